// Round 4
// baseline (375.497 us; speedup 1.0000x reference)
//
#include <hip/hip_runtime.h>
#include <math.h>

#define N_NODES 100000
#define R_REL   1000
#define T_TRI   600000
#define D_DIM   128
#define OUT_STRIDE 640

__device__ __forceinline__ float wave_sum(float v) {
    #pragma unroll
    for (int off = 32; off > 0; off >>= 1) v += __shfl_xor(v, off);
    return v;
}
__device__ __forceinline__ float wave_max(float v) {
    #pragma unroll
    for (int off = 32; off > 0; off >>= 1) v = fmaxf(v, __shfl_xor(v, off));
    return v;
}
__device__ __forceinline__ float sub8_sum(float v) {
    v += __shfl_xor(v, 1); v += __shfl_xor(v, 2); v += __shfl_xor(v, 4);
    return v;
}
__device__ __forceinline__ float fast_tanh(float x) {
    float e = __expf(2.f * x);
    return 1.f - __fdividef(2.f, e + 1.f);
}
__device__ __forceinline__ float4 tanh4(float4 v) {
    float4 o; o.x = fast_tanh(v.x); o.y = fast_tanh(v.y);
    o.z = fast_tanh(v.z); o.w = fast_tanh(v.w);
    return o;
}

__global__ void k_tanh(const float* __restrict__ feat, float* __restrict__ out) {
    int i = blockIdx.x * blockDim.x + threadIdx.x;
    if (i >= N_NODES * D_DIM / 4) return;
    int n  = i / (D_DIM / 4);
    int d4 = i % (D_DIM / 4);
    float4 v = reinterpret_cast<const float4*>(feat)[i];
    reinterpret_cast<float4*>(out + (size_t)n * OUT_STRIDE)[d4] = tanh4(v);
}

__global__ void k_relprep(const float* __restrict__ rel, const float* __restrict__ attk,
                          float* __restrict__ norm_r, float* __restrict__ dotk) {
    int r = blockIdx.x;
    int lane = threadIdx.x;
    float a0 = rel[r * D_DIM + lane], a1 = rel[r * D_DIM + 64 + lane];
    float nrm = wave_sum(a0 * a0 + a1 * a1);
    float d0  = wave_sum(a0 * attk[lane] + a1 * attk[64 + lane]);
    float d1  = wave_sum(a0 * attk[D_DIM + lane] + a1 * attk[D_DIM + 64 + lane]);
    if (lane == 0) {
        norm_r[r] = sqrtf(nrm);
        dotk[r] = d0;
        dotk[R_REL + r] = d1;
    }
}

__global__ void k_rowptr2(const int* __restrict__ rows_a, const int* __restrict__ rows_b,
                          int* __restrict__ pa, int* __restrict__ pb) {
    int i = blockIdx.x * blockDim.x + threadIdx.x;
    const int* rows; int* p; int n;
    if (i <= N_NODES) { rows = rows_a; p = pa; n = i; }
    else {
        n = i - (N_NODES + 1);
        if (n > N_NODES) return;
        rows = rows_b; p = pb;
    }
    int lo = 0, hi = T_TRI;
    while (lo < hi) { int mid = (lo + hi) >> 1; if (rows[mid] < n) lo = mid + 1; else hi = mid; }
    p[n] = lo;
}

// One wave per row.  8 subgroups x 8 lanes, one triple per subgroup, 16 dims/lane.
// Iter-0 gathers issue BEFORE the softmax reductions.  The tail loop is
// wave-uniform (base < end, beg/end uniform per wave) so every __shfl source
// lane is active; shuffles are hoisted out of ternaries, results masked.
__global__ __launch_bounds__(256) void k_nr_layer(
    float* __restrict__ outbuf, int in_off, int out_off,
    const int* __restrict__ row_ptr,
    const int* __restrict__ col,
    const int* __restrict__ ridx1,
    const float* __restrict__ r_val,
    const float* __restrict__ rel,
    const float* __restrict__ norm_r,
    const float* __restrict__ dotk,
    const float* __restrict__ ha,
    float* __restrict__ proj_out) {
    int lane = threadIdx.x & 63;
    int wid  = (blockIdx.x * blockDim.x + threadIdx.x) >> 6;
    if (wid >= N_NODES) return;
    int beg = row_ptr[wid], end = row_ptr[wid + 1];
    int deg = end - beg;
    float* orow = outbuf + (size_t)wid * OUT_STRIDE + out_off;
    int sg = lane >> 3, sl = lane & 7;

    if (deg == 0) {
        if (lane < 32) { float4 z = {0.f,0.f,0.f,0.f}; ((float4*)orow)[lane] = z; }
        if (ha != nullptr && lane == 0) proj_out[wid] = 0.f;
        return;
    }

    // ---- pass A per-lane inputs (lane i owns triple beg+i) ----
    int  t0 = beg + lane;
    bool va = t0 < end;
    int  ta = va ? t0 : beg;
    int  rt0 = ridx1[ta];
    float rv0 = r_val[ta];
    float sc0 = rv0 / fmaxf(rv0 * norm_r[rt0], 1e-12f);
    float l0  = sc0 * dotk[rt0];

    // ---- iter 0: issue gathers before the reduction chains ----
    bool vb0 = (beg + sg) < end;
    int  bsel = vb0 ? sg : 0;
    int  tbc  = vb0 ? (beg + sg) : beg;
    int  cb   = col[tbc];
    int  rtb  = __shfl(rt0, bsel);
    float scb = __shfl(sc0, bsel);
    const float4* frow4 = (const float4*)(outbuf + (size_t)cb * OUT_STRIDE + in_off);
    const float4* rrow4 = (const float4*)(rel + (size_t)rtb * D_DIM);
    float4 n0 = frow4[sl], n1 = frow4[8 + sl], n2 = frow4[16 + sl], n3 = frow4[24 + sl];
    float4 r0 = rrow4[sl], r1 = rrow4[8 + sl], r2 = rrow4[16 + sl], r3 = rrow4[24 + sl];

    // ---- pass A reductions (overlap in-flight gathers) ----
    float m = wave_max(va ? l0 : -INFINITY);
    float e0 = va ? __expf(l0 - m) : 0.f;
    float inv_s = 1.f / wave_sum(e0);

    // ---- iter 0 compute ----
    float e_b = __shfl(e0, bsel);               // unconditional shuffle
    float w = vb0 ? e_b * inv_s : 0.f;
    float pd = n0.x*r0.x + n0.y*r0.y + n0.z*r0.z + n0.w*r0.w
             + n1.x*r1.x + n1.y*r1.y + n1.z*r1.z + n1.w*r1.w
             + n2.x*r2.x + n2.y*r2.y + n2.z*r2.z + n2.w*r2.w
             + n3.x*r3.x + n3.y*r3.y + n3.z*r3.z + n3.w*r3.w;
    pd = sub8_sum(pd);
    float f = 2.f * scb * scb * pd;
    float4 a0, a1, a2, a3;
    a0.x = w*(n0.x - f*r0.x); a0.y = w*(n0.y - f*r0.y); a0.z = w*(n0.z - f*r0.z); a0.w = w*(n0.w - f*r0.w);
    a1.x = w*(n1.x - f*r1.x); a1.y = w*(n1.y - f*r1.y); a1.z = w*(n1.z - f*r1.z); a1.w = w*(n1.w - f*r1.w);
    a2.x = w*(n2.x - f*r2.x); a2.y = w*(n2.y - f*r2.y); a2.z = w*(n2.z - f*r2.z); a2.w = w*(n2.w - f*r2.w);
    a3.x = w*(n3.x - f*r3.x); a3.y = w*(n3.y - f*r3.y); a3.z = w*(n3.z - f*r3.z); a3.w = w*(n3.w - f*r3.w);

    // ---- tail (deg > 8): WAVE-UNIFORM loop, all lanes stay active ----
    for (int base = beg + 8; base < end; base += 8) {
        int t = base + sg;
        bool valid = t < end;
        int idx = t - beg;                      // [base-beg, base-beg+7]: never straddles 64
        int tc = valid ? t : beg;
        int rt; float sc, wt;
        if (idx < 64) {
            int srcl = valid ? idx : 0;
            rt = __shfl(rt0, srcl);             // unconditional shuffles, masked results
            sc = __shfl(sc0, srcl);
            float es = __shfl(e0, srcl);
            wt = valid ? es * inv_s : 0.f;
        } else {                                // deg > 64 fallback (not hit on this data)
            rt = ridx1[tc]; float rv = r_val[tc];
            sc = rv / fmaxf(rv * norm_r[rt], 1e-12f);
            wt = valid ? __expf(sc * dotk[rt] - m) * inv_s : 0.f;
        }
        int c = col[tc];
        const float4* fr = (const float4*)(outbuf + (size_t)c * OUT_STRIDE + in_off);
        const float4* rr = (const float4*)(rel + (size_t)rt * D_DIM);
        float4 b0 = fr[sl], b1 = fr[8 + sl], b2 = fr[16 + sl], b3 = fr[24 + sl];
        float4 q0 = rr[sl], q1 = rr[8 + sl], q2 = rr[16 + sl], q3 = rr[24 + sl];
        float pdt = b0.x*q0.x + b0.y*q0.y + b0.z*q0.z + b0.w*q0.w
                  + b1.x*q1.x + b1.y*q1.y + b1.z*q1.z + b1.w*q1.w
                  + b2.x*q2.x + b2.y*q2.y + b2.z*q2.z + b2.w*q2.w
                  + b3.x*q3.x + b3.y*q3.y + b3.z*q3.z + b3.w*q3.w;
        pdt = sub8_sum(pdt);
        float ft = 2.f * sc * sc * pdt;
        a0.x += wt*(b0.x - ft*q0.x); a0.y += wt*(b0.y - ft*q0.y); a0.z += wt*(b0.z - ft*q0.z); a0.w += wt*(b0.w - ft*q0.w);
        a1.x += wt*(b1.x - ft*q1.x); a1.y += wt*(b1.y - ft*q1.y); a1.z += wt*(b1.z - ft*q1.z); a1.w += wt*(b1.w - ft*q1.w);
        a2.x += wt*(b2.x - ft*q2.x); a2.y += wt*(b2.y - ft*q2.y); a2.z += wt*(b2.z - ft*q2.z); a2.w += wt*(b2.w - ft*q2.w);
        a3.x += wt*(b3.x - ft*q3.x); a3.y += wt*(b3.y - ft*q3.y); a3.z += wt*(b3.z - ft*q3.z); a3.w += wt*(b3.w - ft*q3.w);
    }

#define CMB(c) { c += __shfl_xor(c, 8); c += __shfl_xor(c, 16); c += __shfl_xor(c, 32); }
    CMB(a0.x) CMB(a0.y) CMB(a0.z) CMB(a0.w)
    CMB(a1.x) CMB(a1.y) CMB(a1.z) CMB(a1.w)
    CMB(a2.x) CMB(a2.y) CMB(a2.z) CMB(a2.w)
    CMB(a3.x) CMB(a3.y) CMB(a3.z) CMB(a3.w)
#undef CMB
    int q = sg & 3;
    float4 sel = (q == 0) ? a0 : (q == 1) ? a1 : (q == 2) ? a2 : a3;
    float4 tv = tanh4(sel);
    if (lane < 32) ((float4*)orow)[lane] = tv;
    if (ha != nullptr) {
        const float4* ha4 = (const float4*)ha;
        float4 h = ha4[lane & 31];
        float pdp = (lane < 32) ? (tv.x*h.x + tv.y*h.y + tv.z*h.z + tv.w*h.w) : 0.f;
        pdp = wave_sum(pdp);
        if (lane == 0) proj_out[wid] = pdp;
    }
}

__global__ __launch_bounds__(256) void k_high_layer(
    float* __restrict__ outbuf, int in_off, int out_off,
    const int* __restrict__ row_ptr,
    const int* __restrict__ hcol,
    const float* __restrict__ proj,
    const float* __restrict__ ha,
    float* __restrict__ proj_out) {
    int lane = threadIdx.x & 63;
    int wid  = (blockIdx.x * blockDim.x + threadIdx.x) >> 6;
    if (wid >= N_NODES) return;
    int beg = row_ptr[wid], end = row_ptr[wid + 1];
    int deg = end - beg;
    float* orow = outbuf + (size_t)wid * OUT_STRIDE + out_off;
    int sg = lane >> 3, sl = lane & 7;

    if (deg == 0) {
        if (lane < 32) { float4 z = {0.f,0.f,0.f,0.f}; ((float4*)orow)[lane] = z; }
        if (ha != nullptr && lane == 0) proj_out[wid] = 0.f;
        return;
    }

    int  t0 = beg + lane;
    bool va = t0 < end;
    int  ta = va ? t0 : beg;
    int  c0 = hcol[ta];
    float l0 = proj[c0];

    bool vb0 = (beg + sg) < end;
    int  bsel = vb0 ? sg : 0;
    int  cb = __shfl(c0, bsel);
    const float4* frow4 = (const float4*)(outbuf + (size_t)cb * OUT_STRIDE + in_off);
    float4 n0 = frow4[sl], n1 = frow4[8 + sl], n2 = frow4[16 + sl], n3 = frow4[24 + sl];

    float m = wave_max(va ? l0 : -INFINITY);
    float e0 = va ? __expf(l0 - m) : 0.f;
    float inv_s = 1.f / wave_sum(e0);

    float e_b = __shfl(e0, bsel);
    float w = vb0 ? e_b * inv_s : 0.f;
    float4 a0, a1, a2, a3;
    a0.x = w*n0.x; a0.y = w*n0.y; a0.z = w*n0.z; a0.w = w*n0.w;
    a1.x = w*n1.x; a1.y = w*n1.y; a1.z = w*n1.z; a1.w = w*n1.w;
    a2.x = w*n2.x; a2.y = w*n2.y; a2.z = w*n2.z; a2.w = w*n2.w;
    a3.x = w*n3.x; a3.y = w*n3.y; a3.z = w*n3.z; a3.w = w*n3.w;

    for (int base = beg + 8; base < end; base += 8) {
        int t = base + sg;
        bool valid = t < end;
        int idx = t - beg;
        int tc = valid ? t : beg;
        int c; float wt;
        if (idx < 64) {
            int srcl = valid ? idx : 0;
            c = __shfl(c0, srcl);
            float es = __shfl(e0, srcl);
            wt = valid ? es * inv_s : 0.f;
        } else {
            c = hcol[tc];
            wt = valid ? __expf(proj[c] - m) * inv_s : 0.f;
        }
        const float4* fr = (const float4*)(outbuf + (size_t)c * OUT_STRIDE + in_off);
        float4 b0 = fr[sl], b1 = fr[8 + sl], b2 = fr[16 + sl], b3 = fr[24 + sl];
        a0.x += wt*b0.x; a0.y += wt*b0.y; a0.z += wt*b0.z; a0.w += wt*b0.w;
        a1.x += wt*b1.x; a1.y += wt*b1.y; a1.z += wt*b1.z; a1.w += wt*b1.w;
        a2.x += wt*b2.x; a2.y += wt*b2.y; a2.z += wt*b2.z; a2.w += wt*b2.w;
        a3.x += wt*b3.x; a3.y += wt*b3.y; a3.z += wt*b3.z; a3.w += wt*b3.w;
    }

#define CMB(c) { c += __shfl_xor(c, 8); c += __shfl_xor(c, 16); c += __shfl_xor(c, 32); }
    CMB(a0.x) CMB(a0.y) CMB(a0.z) CMB(a0.w)
    CMB(a1.x) CMB(a1.y) CMB(a1.z) CMB(a1.w)
    CMB(a2.x) CMB(a2.y) CMB(a2.z) CMB(a2.w)
    CMB(a3.x) CMB(a3.y) CMB(a3.z) CMB(a3.w)
#undef CMB
    int q = sg & 3;
    float4 sel = (q == 0) ? a0 : (q == 1) ? a1 : (q == 2) ? a2 : a3;
    float4 tv = tanh4(sel);
    if (lane < 32) ((float4*)orow)[lane] = tv;
    if (ha != nullptr) {
        const float4* ha4 = (const float4*)ha;
        float4 h = ha4[lane & 31];
        float pdp = (lane < 32) ? (tv.x*h.x + tv.y*h.y + tv.z*h.z + tv.w*h.w) : 0.f;
        pdp = wave_sum(pdp);
        if (lane == 0) proj_out[wid] = pdp;
    }
}

extern "C" void kernel_launch(void* const* d_in, const int* in_sizes, int n_in,
                              void* d_out, int out_size, void* d_ws, size_t ws_size,
                              hipStream_t stream) {
    const float* features  = (const float*)d_in[0];
    const float* rel_emb   = (const float*)d_in[1];
    const float* r_val     = (const float*)d_in[2];
    const float* attk      = (const float*)d_in[3];
    const float* high_atts = (const float*)d_in[4];
    const int*   adj       = (const int*)d_in[5];
    const int*   r_index   = (const int*)d_in[6];
    const int*   high_nei  = (const int*)d_in[7];
    float* out = (float*)d_out;

    char* ws = (char*)d_ws;
    int*   row_ptr_adj  = (int*)ws;   ws += (N_NODES + 1) * sizeof(int);
    int*   row_ptr_high = (int*)ws;   ws += (N_NODES + 1) * sizeof(int);
    float* norm_r       = (float*)ws; ws += R_REL * sizeof(float);
    float* dotk         = (float*)ws; ws += 2 * R_REL * sizeof(float);
    float* proj0        = (float*)ws; ws += N_NODES * sizeof(float);
    float* proj1        = (float*)ws; ws += N_NODES * sizeof(float);

    k_tanh<<<(N_NODES * D_DIM / 4 + 255) / 256, 256, 0, stream>>>(features, out);
    k_relprep<<<R_REL, 64, 0, stream>>>(rel_emb, attk, norm_r, dotk);
    k_rowptr2<<<(2 * (N_NODES + 1) + 255) / 256, 256, 0, stream>>>(
        adj, high_nei, row_ptr_adj, row_ptr_high);

    int row_blocks = (N_NODES + 3) / 4;

    k_nr_layer<<<row_blocks, 256, 0, stream>>>(
        out, 0 * D_DIM, 1 * D_DIM,
        row_ptr_adj, adj + T_TRI, r_index + T_TRI, r_val,
        rel_emb, norm_r, dotk + 0 * R_REL, nullptr, nullptr);
    k_nr_layer<<<row_blocks, 256, 0, stream>>>(
        out, 1 * D_DIM, 2 * D_DIM,
        row_ptr_adj, adj + T_TRI, r_index + T_TRI, r_val,
        rel_emb, norm_r, dotk + 1 * R_REL, high_atts + 0 * D_DIM, proj0);
    k_high_layer<<<row_blocks, 256, 0, stream>>>(
        out, 2 * D_DIM, 3 * D_DIM,
        row_ptr_high, high_nei + T_TRI, proj0, high_atts + 1 * D_DIM, proj1);
    k_high_layer<<<row_blocks, 256, 0, stream>>>(
        out, 3 * D_DIM, 4 * D_DIM,
        row_ptr_high, high_nei + T_TRI, proj1, nullptr, nullptr);
}

// Round 5
// 313.640 us; speedup vs baseline: 1.1972x; 1.1972x over previous
//
#include <hip/hip_runtime.h>
#include <math.h>

#define N_NODES 100000
#define R_REL   1000
#define T_TRI   600000
#define D_DIM   128
#define OUT_STRIDE 640

__device__ __forceinline__ float wave_sum(float v) {
    #pragma unroll
    for (int off = 32; off > 0; off >>= 1) v += __shfl_xor(v, off);
    return v;
}
__device__ __forceinline__ float wave_max(float v) {
    #pragma unroll
    for (int off = 32; off > 0; off >>= 1) v = fmaxf(v, __shfl_xor(v, off));
    return v;
}
__device__ __forceinline__ float sub16_sum(float v) {
    v += __shfl_xor(v, 1); v += __shfl_xor(v, 2);
    v += __shfl_xor(v, 4); v += __shfl_xor(v, 8);
    return v;
}
__device__ __forceinline__ float fast_tanh(float x) {
    float e = __expf(2.f * x);
    return 1.f - __fdividef(2.f, e + 1.f);
}
__device__ __forceinline__ float4 tanh4(float4 v) {
    float4 o; o.x = fast_tanh(v.x); o.y = fast_tanh(v.y);
    o.z = fast_tanh(v.z); o.w = fast_tanh(v.w);
    return o;
}
__device__ __forceinline__ float dot4(float4 a, float4 b) {
    return a.x*b.x + a.y*b.y + a.z*b.z + a.w*b.w;
}

__global__ void k_tanh(const float* __restrict__ feat, float* __restrict__ out) {
    int i = blockIdx.x * blockDim.x + threadIdx.x;
    if (i >= N_NODES * D_DIM / 4) return;
    int n  = i / (D_DIM / 4);
    int d4 = i % (D_DIM / 4);
    float4 v = reinterpret_cast<const float4*>(feat)[i];
    reinterpret_cast<float4*>(out + (size_t)n * OUT_STRIDE)[d4] = tanh4(v);
}

__global__ void k_relprep(const float* __restrict__ rel, const float* __restrict__ attk,
                          float* __restrict__ norm_r, float* __restrict__ dotk) {
    int r = blockIdx.x;
    int lane = threadIdx.x;
    float a0 = rel[r * D_DIM + lane], a1 = rel[r * D_DIM + 64 + lane];
    float nrm = wave_sum(a0 * a0 + a1 * a1);
    float d0  = wave_sum(a0 * attk[lane] + a1 * attk[64 + lane]);
    float d1  = wave_sum(a0 * attk[D_DIM + lane] + a1 * attk[D_DIM + 64 + lane]);
    if (lane == 0) {
        norm_r[r] = sqrtf(nrm);
        dotk[r] = d0;
        dotk[R_REL + r] = d1;
    }
}

__global__ void k_rowptr2(const int* __restrict__ rows_a, const int* __restrict__ rows_b,
                          int* __restrict__ pa, int* __restrict__ pb) {
    int i = blockIdx.x * blockDim.x + threadIdx.x;
    const int* rows; int* p; int n;
    if (i <= N_NODES) { rows = rows_a; p = pa; n = i; }
    else {
        n = i - (N_NODES + 1);
        if (n > N_NODES) return;
        rows = rows_b; p = pb;
    }
    int lo = 0, hi = T_TRI;
    while (lo < hi) { int mid = (lo + hi) >> 1; if (rows[mid] < n) lo = mid + 1; else hi = mid; }
    p[n] = lo;
}

// One wave per row.  4 subgroups x 16 lanes, one triple per subgroup per iter,
// 8 dims/lane (2 float4).  Iter-0 AND iter-1 gathers are issued before the
// pass-A softmax reductions; steady-state loop is 2-deep pipelined and
// wave-uniform (niter = ceil(deg/4) is uniform), weights via LDS broadcast.
__global__ __launch_bounds__(256) void k_nr_layer(
    float* __restrict__ outbuf, int in_off, int out_off,
    const int* __restrict__ row_ptr,
    const int* __restrict__ col,
    const int* __restrict__ ridx1,
    const float* __restrict__ r_val,
    const float* __restrict__ rel,
    const float* __restrict__ norm_r,
    const float* __restrict__ dotk,
    const float* __restrict__ ha,
    float* __restrict__ proj_out) {
    __shared__ float s_w[4][64];
    __shared__ float s_sc[4][64];
    int wslot = threadIdx.x >> 6;
    int lane  = threadIdx.x & 63;
    int wid   = (blockIdx.x * blockDim.x + threadIdx.x) >> 6;
    if (wid >= N_NODES) return;
    int beg = row_ptr[wid], end = row_ptr[wid + 1];
    int deg = end - beg;
    float* orow = outbuf + (size_t)wid * OUT_STRIDE + out_off;
    int sg = lane >> 4, sl = lane & 15;

    if (deg == 0) {
        if (lane < 32) { float4 z = {0.f,0.f,0.f,0.f}; ((float4*)orow)[lane] = z; }
        if (ha != nullptr && lane == 0) proj_out[wid] = 0.f;
        return;
    }

    // ---- pass A per-lane inputs (lane i owns triple beg+i) ----
    int  t0 = beg + lane;
    bool va = t0 < end;
    int  ta = va ? t0 : beg;
    int  rt_a = ridx1[ta];
    float rv_a = r_val[ta];
    float sc_a = rv_a / fmaxf(rv_a * norm_r[rt_a], 1e-12f);
    float l_a  = sc_a * dotk[rt_a];

    // ---- pre-issue pass-B iter0 + iter1 gathers (independent of reductions) ----
    int  tb0 = beg + sg, tb1 = tb0 + 4;
    bool v0 = tb0 < end, v1 = tb1 < end;
    int  tc0 = v0 ? tb0 : beg, tc1 = v1 ? tb1 : beg;
    int  cc0 = col[tc0],   cc1 = col[tc1];
    int  rr0 = ridx1[tc0], rr1 = ridx1[tc1];
    const float4* fp0 = (const float4*)(outbuf + (size_t)cc0 * OUT_STRIDE + in_off);
    const float4* rp0 = (const float4*)(rel + (size_t)rr0 * D_DIM);
    const float4* fp1 = (const float4*)(outbuf + (size_t)cc1 * OUT_STRIDE + in_off);
    const float4* rp1 = (const float4*)(rel + (size_t)rr1 * D_DIM);
    float4 fA = fp0[sl], fB = fp0[16 + sl];
    float4 rA = rp0[sl], rB = rp0[16 + sl];
    float4 gA = fp1[sl], gB = fp1[16 + sl];
    float4 qA = rp1[sl], qB = rp1[16 + sl];

    // ---- pass A reductions (overlap the 8 in-flight gathers) ----
    float lmax = va ? l_a : -INFINITY;
    for (int t = t0 + 64; t < end; t += 64) {          // deg>64 guard (no-op here)
        int rt = ridx1[t]; float rv = r_val[t];
        float sc = rv / fmaxf(rv * norm_r[rt], 1e-12f);
        lmax = fmaxf(lmax, sc * dotk[rt]);
    }
    float m = wave_max(lmax);
    float e_a = va ? __expf(l_a - m) : 0.f;
    float lsum = e_a;
    for (int t = t0 + 64; t < end; t += 64) {
        int rt = ridx1[t]; float rv = r_val[t];
        float sc = rv / fmaxf(rv * norm_r[rt], 1e-12f);
        lsum += __expf(sc * dotk[rt] - m);
    }
    float inv_s = 1.f / wave_sum(lsum);
    s_w[wslot][lane]  = e_a * inv_s;
    s_sc[wslot][lane] = sc_a;
    // same wave writes & reads: no barrier needed

    // ---- iter 0 compute ----
    float w0  = v0 ? s_w[wslot][sg] : 0.f;
    float sc0 = s_sc[wslot][sg];
    float pd = dot4(fA, rA) + dot4(fB, rB);
    pd = sub16_sum(pd);
    float f0 = 2.f * sc0 * sc0 * pd;
    float4 a0, a1;
    a0.x = w0*(fA.x - f0*rA.x); a0.y = w0*(fA.y - f0*rA.y);
    a0.z = w0*(fA.z - f0*rA.z); a0.w = w0*(fA.w - f0*rA.w);
    a1.x = w0*(fB.x - f0*rB.x); a1.y = w0*(fB.y - f0*rB.y);
    a1.z = w0*(fB.z - f0*rB.z); a1.w = w0*(fB.w - f0*rB.w);

    // ---- steady state: wave-uniform, 2-deep pipelined ----
    int niter = (deg + 3) >> 2;
    int cur_tc = tc1, cur_rr = rr1; bool cur_v = v1;
    for (int it = 1; it < niter; ++it) {
        // pre-issue iter it+1 (clamped when past end)
        int tb = beg + 4 * (it + 1) + sg;
        bool nv = tb < end;
        int  ntc = nv ? tb : beg;
        int  ncc = col[ntc];
        int  nrr = ridx1[ntc];
        const float4* nfp = (const float4*)(outbuf + (size_t)ncc * OUT_STRIDE + in_off);
        const float4* nrp = (const float4*)(rel + (size_t)nrr * D_DIM);
        float4 nfA = nfp[sl], nfB = nfp[16 + sl];
        float4 nrA = nrp[sl], nrB = nrp[16 + sl];

        // compute iter it with gA,gB,qA,qB
        int idx = 4 * it + sg;
        float w, sc;
        if (idx < 64) {
            w  = cur_v ? s_w[wslot][idx] : 0.f;
            sc = s_sc[wslot][idx];
        } else {
            float rv = r_val[cur_tc];
            sc = rv / fmaxf(rv * norm_r[cur_rr], 1e-12f);
            w  = cur_v ? __expf(sc * dotk[cur_rr] - m) * inv_s : 0.f;
        }
        float pdt = dot4(gA, qA) + dot4(gB, qB);
        pdt = sub16_sum(pdt);
        float ft = 2.f * sc * sc * pdt;
        a0.x += w*(gA.x - ft*qA.x); a0.y += w*(gA.y - ft*qA.y);
        a0.z += w*(gA.z - ft*qA.z); a0.w += w*(gA.w - ft*qA.w);
        a1.x += w*(gB.x - ft*qB.x); a1.y += w*(gB.y - ft*qB.y);
        a1.z += w*(gB.z - ft*qB.z); a1.w += w*(gB.w - ft*qB.w);

        gA = nfA; gB = nfB; qA = nrA; qB = nrB;
        cur_tc = ntc; cur_rr = nrr; cur_v = nv;
    }

    // combine 4 subgroup partials (lanes sl, sl+16, sl+32, sl+48 share dims)
#define CMB(c) { c += __shfl_xor(c, 16); c += __shfl_xor(c, 32); }
    CMB(a0.x) CMB(a0.y) CMB(a0.z) CMB(a0.w)
    CMB(a1.x) CMB(a1.y) CMB(a1.z) CMB(a1.w)
#undef CMB
    float4 tv0 = tanh4(a0), tv1 = tanh4(a1);
    if (sg == 0) ((float4*)orow)[sl] = tv0;
    else if (sg == 1) ((float4*)orow)[16 + sl] = tv1;
    if (ha != nullptr) {
        const float4* ha4 = (const float4*)ha;
        float4 h0 = ha4[sl], h1 = ha4[16 + sl];
        float pdp = dot4(tv0, h0) + dot4(tv1, h1);
        pdp = sub16_sum(pdp);
        if (lane == 0) proj_out[wid] = pdp;
    }
}

__global__ __launch_bounds__(256) void k_high_layer(
    float* __restrict__ outbuf, int in_off, int out_off,
    const int* __restrict__ row_ptr,
    const int* __restrict__ hcol,
    const float* __restrict__ proj,
    const float* __restrict__ ha,
    float* __restrict__ proj_out) {
    __shared__ float s_w[4][64];
    int wslot = threadIdx.x >> 6;
    int lane  = threadIdx.x & 63;
    int wid   = (blockIdx.x * blockDim.x + threadIdx.x) >> 6;
    if (wid >= N_NODES) return;
    int beg = row_ptr[wid], end = row_ptr[wid + 1];
    int deg = end - beg;
    float* orow = outbuf + (size_t)wid * OUT_STRIDE + out_off;
    int sg = lane >> 4, sl = lane & 15;

    if (deg == 0) {
        if (lane < 32) { float4 z = {0.f,0.f,0.f,0.f}; ((float4*)orow)[lane] = z; }
        if (ha != nullptr && lane == 0) proj_out[wid] = 0.f;
        return;
    }

    int  t0 = beg + lane;
    bool va = t0 < end;
    int  ta = va ? t0 : beg;
    int  c_a = hcol[ta];
    float l_a = proj[c_a];

    // pre-issue iter0 + iter1 feature gathers
    int  tb0 = beg + sg, tb1 = tb0 + 4;
    bool v0 = tb0 < end, v1 = tb1 < end;
    int  tc0 = v0 ? tb0 : beg, tc1 = v1 ? tb1 : beg;
    int  cc0 = hcol[tc0], cc1 = hcol[tc1];
    const float4* fp0 = (const float4*)(outbuf + (size_t)cc0 * OUT_STRIDE + in_off);
    const float4* fp1 = (const float4*)(outbuf + (size_t)cc1 * OUT_STRIDE + in_off);
    float4 fA = fp0[sl], fB = fp0[16 + sl];
    float4 gA = fp1[sl], gB = fp1[16 + sl];

    float lmax = va ? l_a : -INFINITY;
    for (int t = t0 + 64; t < end; t += 64)            // deg>64 guard
        lmax = fmaxf(lmax, proj[hcol[t]]);
    float m = wave_max(lmax);
    float e_a = va ? __expf(l_a - m) : 0.f;
    float lsum = e_a;
    for (int t = t0 + 64; t < end; t += 64)
        lsum += __expf(proj[hcol[t]] - m);
    float inv_s = 1.f / wave_sum(lsum);
    s_w[wslot][lane] = e_a * inv_s;

    float w0 = v0 ? s_w[wslot][sg] : 0.f;
    float4 a0, a1;
    a0.x = w0*fA.x; a0.y = w0*fA.y; a0.z = w0*fA.z; a0.w = w0*fA.w;
    a1.x = w0*fB.x; a1.y = w0*fB.y; a1.z = w0*fB.z; a1.w = w0*fB.w;

    int niter = (deg + 3) >> 2;
    int cur_cc = cc1; bool cur_v = v1;
    for (int it = 1; it < niter; ++it) {
        int tb = beg + 4 * (it + 1) + sg;
        bool nv = tb < end;
        int  ntc = nv ? tb : beg;
        int  ncc = hcol[ntc];
        const float4* nfp = (const float4*)(outbuf + (size_t)ncc * OUT_STRIDE + in_off);
        float4 nfA = nfp[sl], nfB = nfp[16 + sl];

        int idx = 4 * it + sg;
        float w;
        if (idx < 64) w = cur_v ? s_w[wslot][idx] : 0.f;
        else          w = cur_v ? __expf(proj[cur_cc] - m) * inv_s : 0.f;
        a0.x += w*gA.x; a0.y += w*gA.y; a0.z += w*gA.z; a0.w += w*gA.w;
        a1.x += w*gB.x; a1.y += w*gB.y; a1.z += w*gB.z; a1.w += w*gB.w;

        gA = nfA; gB = nfB; cur_cc = ncc; cur_v = nv;
    }

#define CMB(c) { c += __shfl_xor(c, 16); c += __shfl_xor(c, 32); }
    CMB(a0.x) CMB(a0.y) CMB(a0.z) CMB(a0.w)
    CMB(a1.x) CMB(a1.y) CMB(a1.z) CMB(a1.w)
#undef CMB
    float4 tv0 = tanh4(a0), tv1 = tanh4(a1);
    if (sg == 0) ((float4*)orow)[sl] = tv0;
    else if (sg == 1) ((float4*)orow)[16 + sl] = tv1;
    if (ha != nullptr) {
        const float4* ha4 = (const float4*)ha;
        float4 h0 = ha4[sl], h1 = ha4[16 + sl];
        float pdp = dot4(tv0, h0) + dot4(tv1, h1);
        pdp = sub16_sum(pdp);
        if (lane == 0) proj_out[wid] = pdp;
    }
}

extern "C" void kernel_launch(void* const* d_in, const int* in_sizes, int n_in,
                              void* d_out, int out_size, void* d_ws, size_t ws_size,
                              hipStream_t stream) {
    const float* features  = (const float*)d_in[0];
    const float* rel_emb   = (const float*)d_in[1];
    const float* r_val     = (const float*)d_in[2];
    const float* attk      = (const float*)d_in[3];
    const float* high_atts = (const float*)d_in[4];
    const int*   adj       = (const int*)d_in[5];
    const int*   r_index   = (const int*)d_in[6];
    const int*   high_nei  = (const int*)d_in[7];
    float* out = (float*)d_out;

    char* ws = (char*)d_ws;
    int*   row_ptr_adj  = (int*)ws;   ws += (N_NODES + 1) * sizeof(int);
    int*   row_ptr_high = (int*)ws;   ws += (N_NODES + 1) * sizeof(int);
    float* norm_r       = (float*)ws; ws += R_REL * sizeof(float);
    float* dotk         = (float*)ws; ws += 2 * R_REL * sizeof(float);
    float* proj0        = (float*)ws; ws += N_NODES * sizeof(float);
    float* proj1        = (float*)ws; ws += N_NODES * sizeof(float);

    k_tanh<<<(N_NODES * D_DIM / 4 + 255) / 256, 256, 0, stream>>>(features, out);
    k_relprep<<<R_REL, 64, 0, stream>>>(rel_emb, attk, norm_r, dotk);
    k_rowptr2<<<(2 * (N_NODES + 1) + 255) / 256, 256, 0, stream>>>(
        adj, high_nei, row_ptr_adj, row_ptr_high);

    int row_blocks = (N_NODES + 3) / 4;

    k_nr_layer<<<row_blocks, 256, 0, stream>>>(
        out, 0 * D_DIM, 1 * D_DIM,
        row_ptr_adj, adj + T_TRI, r_index + T_TRI, r_val,
        rel_emb, norm_r, dotk + 0 * R_REL, nullptr, nullptr);
    k_nr_layer<<<row_blocks, 256, 0, stream>>>(
        out, 1 * D_DIM, 2 * D_DIM,
        row_ptr_adj, adj + T_TRI, r_index + T_TRI, r_val,
        rel_emb, norm_r, dotk + 1 * R_REL, high_atts + 0 * D_DIM, proj0);
    k_high_layer<<<row_blocks, 256, 0, stream>>>(
        out, 2 * D_DIM, 3 * D_DIM,
        row_ptr_high, high_nei + T_TRI, proj0, high_atts + 1 * D_DIM, proj1);
    k_high_layer<<<row_blocks, 256, 0, stream>>>(
        out, 3 * D_DIM, 4 * D_DIM,
        row_ptr_high, high_nei + T_TRI, proj1, nullptr, nullptr);
}

// Round 6
// 298.552 us; speedup vs baseline: 1.2577x; 1.0505x over previous
//
#include <hip/hip_runtime.h>
#include <math.h>

#define N_NODES 100000
#define R_REL   1000
#define T_TRI   600000
#define D_DIM   128
#define OUT_STRIDE 640

typedef unsigned int  u32;
typedef unsigned short u16;

__device__ __forceinline__ float wave_sum(float v) {
    #pragma unroll
    for (int off = 32; off > 0; off >>= 1) v += __shfl_xor(v, off);
    return v;
}
__device__ __forceinline__ float wave_max(float v) {
    #pragma unroll
    for (int off = 32; off > 0; off >>= 1) v = fmaxf(v, __shfl_xor(v, off));
    return v;
}
__device__ __forceinline__ float sub16_sum(float v) {
    v += __shfl_xor(v, 1); v += __shfl_xor(v, 2);
    v += __shfl_xor(v, 4); v += __shfl_xor(v, 8);
    return v;
}
__device__ __forceinline__ float fast_tanh(float x) {
    float e = __expf(2.f * x);
    return 1.f - __fdividef(2.f, e + 1.f);
}
__device__ __forceinline__ float4 tanh4(float4 v) {
    float4 o; o.x = fast_tanh(v.x); o.y = fast_tanh(v.y);
    o.z = fast_tanh(v.z); o.w = fast_tanh(v.w);
    return o;
}
__device__ __forceinline__ float dot4(float4 a, float4 b) {
    return a.x*b.x + a.y*b.y + a.z*b.z + a.w*b.w;
}
// bf16 helpers: packed pairs, little-endian (elem 2i low, 2i+1 high), RNE pack
__device__ __forceinline__ u32 bfr(float x) {
    u32 u = __float_as_uint(x);
    return (u + 0x7fffu + ((u >> 16) & 1u)) >> 16;
}
__device__ __forceinline__ uint2 pack_bf4(float4 v) {
    uint2 p;
    p.x = bfr(v.x) | (bfr(v.y) << 16);
    p.y = bfr(v.z) | (bfr(v.w) << 16);
    return p;
}
__device__ __forceinline__ void unpack_bf8(uint4 v, float f[8]) {
    f[0] = __uint_as_float(v.x << 16); f[1] = __uint_as_float(v.x & 0xffff0000u);
    f[2] = __uint_as_float(v.y << 16); f[3] = __uint_as_float(v.y & 0xffff0000u);
    f[4] = __uint_as_float(v.z << 16); f[5] = __uint_as_float(v.z & 0xffff0000u);
    f[6] = __uint_as_float(v.w << 16); f[7] = __uint_as_float(v.w & 0xffff0000u);
}

// chunk0: f32 to out + bf16 copy to ws
__global__ void k_tanh(const float* __restrict__ feat, float* __restrict__ out,
                       u16* __restrict__ bf0) {
    int i = blockIdx.x * blockDim.x + threadIdx.x;
    if (i >= N_NODES * D_DIM / 4) return;
    int n  = i / (D_DIM / 4);
    int d4 = i % (D_DIM / 4);
    float4 v = reinterpret_cast<const float4*>(feat)[i];
    float4 t = tanh4(v);
    reinterpret_cast<float4*>(out + (size_t)n * OUT_STRIDE)[d4] = t;
    reinterpret_cast<uint2*>(bf0 + (size_t)n * D_DIM)[d4] = pack_bf4(t);
}

__global__ void k_relprep(const float* __restrict__ rel, const float* __restrict__ attk,
                          float* __restrict__ norm_r, float* __restrict__ dotk) {
    int r = blockIdx.x;
    int lane = threadIdx.x;
    float a0 = rel[r * D_DIM + lane], a1 = rel[r * D_DIM + 64 + lane];
    float nrm = wave_sum(a0 * a0 + a1 * a1);
    float d0  = wave_sum(a0 * attk[lane] + a1 * attk[64 + lane]);
    float d1  = wave_sum(a0 * attk[D_DIM + lane] + a1 * attk[D_DIM + 64 + lane]);
    if (lane == 0) {
        norm_r[r] = sqrtf(nrm);
        dotk[r] = d0;
        dotk[R_REL + r] = d1;
    }
}

__global__ void k_pack_rel(const float* __restrict__ rel, u16* __restrict__ relbf) {
    int t = blockIdx.x * blockDim.x + threadIdx.x;
    if (t >= R_REL * 16) return;
    int r = t >> 4, k = t & 15;
    const float4* src = (const float4*)(rel + (size_t)r * D_DIM + k * 8);
    uint2 pa = pack_bf4(src[0]), pb = pack_bf4(src[1]);
    uint4 o; o.x = pa.x; o.y = pa.y; o.z = pb.x; o.w = pb.y;
    ((uint4*)(relbf + (size_t)r * D_DIM))[k] = o;
}

__global__ void k_rowptr2(const int* __restrict__ rows_a, const int* __restrict__ rows_b,
                          int* __restrict__ pa, int* __restrict__ pb) {
    int i = blockIdx.x * blockDim.x + threadIdx.x;
    const int* rows; int* p; int n;
    if (i <= N_NODES) { rows = rows_a; p = pa; n = i; }
    else {
        n = i - (N_NODES + 1);
        if (n > N_NODES) return;
        rows = rows_b; p = pb;
    }
    int lo = 0, hi = T_TRI;
    while (lo < hi) { int mid = (lo + hi) >> 1; if (rows[mid] < n) lo = mid + 1; else hi = mid; }
    p[n] = lo;
}

// One wave per row, 4 subgroups x 16 lanes, one triple/subgroup/iter, 8 dims/lane.
// Gathers read bf16 rows (one uint4 per lane per operand); math in f32.
__global__ __launch_bounds__(256) void k_nr_layer(
    float* __restrict__ outbuf, int out_off,
    const u16* __restrict__ in_bf,
    u16* __restrict__ out_bf,           // nullable
    const int* __restrict__ row_ptr,
    const int* __restrict__ col,
    const int* __restrict__ ridx1,
    const float* __restrict__ r_val,
    const u16* __restrict__ rel_bf,
    const float* __restrict__ norm_r,
    const float* __restrict__ dotk,
    const float* __restrict__ ha,       // nullable
    float* __restrict__ proj_out) {
    __shared__ float s_w[4][64];
    __shared__ float s_sc[4][64];
    int wslot = threadIdx.x >> 6;
    int lane  = threadIdx.x & 63;
    int wid   = (blockIdx.x * blockDim.x + threadIdx.x) >> 6;
    if (wid >= N_NODES) return;
    int beg = row_ptr[wid], end = row_ptr[wid + 1];
    int deg = end - beg;
    float* orow = outbuf + (size_t)wid * OUT_STRIDE + out_off;
    int sg = lane >> 4, sl = lane & 15;

    if (deg == 0) {
        if (lane < 32) { float4 z = {0.f,0.f,0.f,0.f}; ((float4*)orow)[lane] = z; }
        if (out_bf != nullptr && lane < 16) {
            uint4 z = {0u,0u,0u,0u};
            ((uint4*)(out_bf + (size_t)wid * D_DIM))[lane] = z;
        }
        if (ha != nullptr && lane == 0) proj_out[wid] = 0.f;
        return;
    }

    // ---- pass A per-lane inputs (lane i owns triple beg+i) ----
    int  t0 = beg + lane;
    bool va = t0 < end;
    int  ta = va ? t0 : beg;
    int  rt_a = ridx1[ta];
    float rv_a = r_val[ta];
    float sc_a = rv_a / fmaxf(rv_a * norm_r[rt_a], 1e-12f);
    float l_a  = sc_a * dotk[rt_a];

    // ---- pre-issue iter0 + iter1 gathers (independent of reductions) ----
    int  tb0 = beg + sg, tb1 = tb0 + 4;
    bool v0 = tb0 < end, v1 = tb1 < end;
    int  tc0 = v0 ? tb0 : beg, tc1 = v1 ? tb1 : beg;
    int  cc0 = col[tc0],   cc1 = col[tc1];
    int  rr0 = ridx1[tc0], rr1 = ridx1[tc1];
    uint4 F0 = ((const uint4*)(in_bf  + (size_t)cc0 * D_DIM))[sl];
    uint4 R0 = ((const uint4*)(rel_bf + (size_t)rr0 * D_DIM))[sl];
    uint4 F1 = ((const uint4*)(in_bf  + (size_t)cc1 * D_DIM))[sl];
    uint4 R1 = ((const uint4*)(rel_bf + (size_t)rr1 * D_DIM))[sl];

    // ---- pass A reductions (overlap in-flight gathers) ----
    float lmax = va ? l_a : -INFINITY;
    for (int t = t0 + 64; t < end; t += 64) {          // deg>64 guard
        int rt = ridx1[t]; float rv = r_val[t];
        float sc = rv / fmaxf(rv * norm_r[rt], 1e-12f);
        lmax = fmaxf(lmax, sc * dotk[rt]);
    }
    float m = wave_max(lmax);
    float e_a = va ? __expf(l_a - m) : 0.f;
    float lsum = e_a;
    for (int t = t0 + 64; t < end; t += 64) {
        int rt = ridx1[t]; float rv = r_val[t];
        float sc = rv / fmaxf(rv * norm_r[rt], 1e-12f);
        lsum += __expf(sc * dotk[rt] - m);
    }
    float inv_s = 1.f / wave_sum(lsum);
    s_w[wslot][lane]  = e_a * inv_s;
    s_sc[wslot][lane] = sc_a;
    // same wave writes & reads: no barrier needed

    // ---- iter 0 compute ----
    float w0  = v0 ? s_w[wslot][sg] : 0.f;
    float sc0 = s_sc[wslot][sg];
    float nf[8], rf[8];
    unpack_bf8(F0, nf); unpack_bf8(R0, rf);
    float pd = 0.f;
    #pragma unroll
    for (int j = 0; j < 8; ++j) pd += nf[j] * rf[j];
    pd = sub16_sum(pd);
    float f0 = 2.f * sc0 * sc0 * pd;
    float acc[8];
    #pragma unroll
    for (int j = 0; j < 8; ++j) acc[j] = w0 * (nf[j] - f0 * rf[j]);

    // ---- steady state: wave-uniform, 2-deep pipelined ----
    int niter = (deg + 3) >> 2;
    int cur_tc = tc1, cur_rr = rr1; bool cur_v = v1;
    for (int it = 1; it < niter; ++it) {
        int tb = beg + 4 * (it + 1) + sg;
        bool nv = tb < end;
        int  ntc = nv ? tb : beg;
        int  ncc = col[ntc];
        int  nrr = ridx1[ntc];
        uint4 NF = ((const uint4*)(in_bf  + (size_t)ncc * D_DIM))[sl];
        uint4 NR = ((const uint4*)(rel_bf + (size_t)nrr * D_DIM))[sl];

        int idx = 4 * it + sg;
        float w, sc;
        if (idx < 64) {
            w  = cur_v ? s_w[wslot][idx] : 0.f;
            sc = s_sc[wslot][idx];
        } else {
            float rv = r_val[cur_tc];
            sc = rv / fmaxf(rv * norm_r[cur_rr], 1e-12f);
            w  = cur_v ? __expf(sc * dotk[cur_rr] - m) * inv_s : 0.f;
        }
        float gf[8], qf[8];
        unpack_bf8(F1, gf); unpack_bf8(R1, qf);
        float pdt = 0.f;
        #pragma unroll
        for (int j = 0; j < 8; ++j) pdt += gf[j] * qf[j];
        pdt = sub16_sum(pdt);
        float ft = 2.f * sc * sc * pdt;
        #pragma unroll
        for (int j = 0; j < 8; ++j) acc[j] += w * (gf[j] - ft * qf[j]);

        F1 = NF; R1 = NR;
        cur_tc = ntc; cur_rr = nrr; cur_v = nv;
    }

    // combine 4 subgroup partials (lanes sl, sl+16, sl+32, sl+48 share dims)
    #pragma unroll
    for (int j = 0; j < 8; ++j) {
        acc[j] += __shfl_xor(acc[j], 16);
        acc[j] += __shfl_xor(acc[j], 32);
    }
    float4 tv0 = tanh4(make_float4(acc[0], acc[1], acc[2], acc[3]));
    float4 tv1 = tanh4(make_float4(acc[4], acc[5], acc[6], acc[7]));
    // lane sl owns dims 8sl..8sl+7 -> float4 indices 2sl, 2sl+1
    if (sg == 0) ((float4*)orow)[2 * sl] = tv0;
    else if (sg == 1) ((float4*)orow)[2 * sl + 1] = tv1;
    if (out_bf != nullptr) {
        u16* rowbf = out_bf + (size_t)wid * D_DIM;
        if (sg == 0) ((uint2*)rowbf)[2 * sl] = pack_bf4(tv0);
        else if (sg == 1) ((uint2*)rowbf)[2 * sl + 1] = pack_bf4(tv1);
    }
    if (ha != nullptr) {
        const float4* ha4 = (const float4*)ha;
        float pdp = dot4(tv0, ha4[2 * sl]) + dot4(tv1, ha4[2 * sl + 1]);
        pdp = sub16_sum(pdp);
        if (lane == 0) proj_out[wid] = pdp;
    }
}

__global__ __launch_bounds__(256) void k_high_layer(
    float* __restrict__ outbuf, int out_off,
    const u16* __restrict__ in_bf,
    u16* __restrict__ out_bf,           // nullable
    const int* __restrict__ row_ptr,
    const int* __restrict__ hcol,
    const float* __restrict__ proj,
    const float* __restrict__ ha,       // nullable
    float* __restrict__ proj_out) {
    __shared__ float s_w[4][64];
    int wslot = threadIdx.x >> 6;
    int lane  = threadIdx.x & 63;
    int wid   = (blockIdx.x * blockDim.x + threadIdx.x) >> 6;
    if (wid >= N_NODES) return;
    int beg = row_ptr[wid], end = row_ptr[wid + 1];
    int deg = end - beg;
    float* orow = outbuf + (size_t)wid * OUT_STRIDE + out_off;
    int sg = lane >> 4, sl = lane & 15;

    if (deg == 0) {
        if (lane < 32) { float4 z = {0.f,0.f,0.f,0.f}; ((float4*)orow)[lane] = z; }
        if (out_bf != nullptr && lane < 16) {
            uint4 z = {0u,0u,0u,0u};
            ((uint4*)(out_bf + (size_t)wid * D_DIM))[lane] = z;
        }
        if (ha != nullptr && lane == 0) proj_out[wid] = 0.f;
        return;
    }

    int  t0 = beg + lane;
    bool va = t0 < end;
    int  ta = va ? t0 : beg;
    int  c_a = hcol[ta];
    float l_a = proj[c_a];

    // pre-issue iter0 + iter1 gathers
    int  tb0 = beg + sg, tb1 = tb0 + 4;
    bool v0 = tb0 < end, v1 = tb1 < end;
    int  tc0 = v0 ? tb0 : beg, tc1 = v1 ? tb1 : beg;
    int  cc0 = hcol[tc0], cc1 = hcol[tc1];
    uint4 F0 = ((const uint4*)(in_bf + (size_t)cc0 * D_DIM))[sl];
    uint4 F1 = ((const uint4*)(in_bf + (size_t)cc1 * D_DIM))[sl];

    float lmax = va ? l_a : -INFINITY;
    for (int t = t0 + 64; t < end; t += 64)            // deg>64 guard
        lmax = fmaxf(lmax, proj[hcol[t]]);
    float m = wave_max(lmax);
    float e_a = va ? __expf(l_a - m) : 0.f;
    float lsum = e_a;
    for (int t = t0 + 64; t < end; t += 64)
        lsum += __expf(proj[hcol[t]] - m);
    float inv_s = 1.f / wave_sum(lsum);
    s_w[wslot][lane] = e_a * inv_s;

    float w0 = v0 ? s_w[wslot][sg] : 0.f;
    float nf[8];
    unpack_bf8(F0, nf);
    float acc[8];
    #pragma unroll
    for (int j = 0; j < 8; ++j) acc[j] = w0 * nf[j];

    int niter = (deg + 3) >> 2;
    int cur_cc = cc1; bool cur_v = v1;
    for (int it = 1; it < niter; ++it) {
        int tb = beg + 4 * (it + 1) + sg;
        bool nv = tb < end;
        int  ntc = nv ? tb : beg;
        int  ncc = hcol[ntc];
        uint4 NF = ((const uint4*)(in_bf + (size_t)ncc * D_DIM))[sl];

        int idx = 4 * it + sg;
        float w;
        if (idx < 64) w = cur_v ? s_w[wslot][idx] : 0.f;
        else          w = cur_v ? __expf(proj[cur_cc] - m) * inv_s : 0.f;
        float gf[8];
        unpack_bf8(F1, gf);
        #pragma unroll
        for (int j = 0; j < 8; ++j) acc[j] += w * gf[j];

        F1 = NF; cur_cc = ncc; cur_v = nv;
    }

    #pragma unroll
    for (int j = 0; j < 8; ++j) {
        acc[j] += __shfl_xor(acc[j], 16);
        acc[j] += __shfl_xor(acc[j], 32);
    }
    float4 tv0 = tanh4(make_float4(acc[0], acc[1], acc[2], acc[3]));
    float4 tv1 = tanh4(make_float4(acc[4], acc[5], acc[6], acc[7]));
    if (sg == 0) ((float4*)orow)[2 * sl] = tv0;
    else if (sg == 1) ((float4*)orow)[2 * sl + 1] = tv1;
    if (out_bf != nullptr) {
        u16* rowbf = out_bf + (size_t)wid * D_DIM;
        if (sg == 0) ((uint2*)rowbf)[2 * sl] = pack_bf4(tv0);
        else if (sg == 1) ((uint2*)rowbf)[2 * sl + 1] = pack_bf4(tv1);
    }
    if (ha != nullptr) {
        const float4* ha4 = (const float4*)ha;
        float pdp = dot4(tv0, ha4[2 * sl]) + dot4(tv1, ha4[2 * sl + 1]);
        pdp = sub16_sum(pdp);
        if (lane == 0) proj_out[wid] = pdp;
    }
}

extern "C" void kernel_launch(void* const* d_in, const int* in_sizes, int n_in,
                              void* d_out, int out_size, void* d_ws, size_t ws_size,
                              hipStream_t stream) {
    const float* features  = (const float*)d_in[0];
    const float* rel_emb   = (const float*)d_in[1];
    const float* r_val     = (const float*)d_in[2];
    const float* attk      = (const float*)d_in[3];
    const float* high_atts = (const float*)d_in[4];
    const int*   adj       = (const int*)d_in[5];
    const int*   r_index   = (const int*)d_in[6];
    const int*   high_nei  = (const int*)d_in[7];
    float* out = (float*)d_out;

    char* ws = (char*)d_ws;
    auto take = [&](size_t bytes) -> char* {
        char* p = ws;
        ws += (bytes + 255) & ~(size_t)255;
        return p;
    };
    int*   row_ptr_adj  = (int*)take((N_NODES + 1) * sizeof(int));
    int*   row_ptr_high = (int*)take((N_NODES + 1) * sizeof(int));
    float* norm_r       = (float*)take(R_REL * sizeof(float));
    float* dotk         = (float*)take(2 * R_REL * sizeof(float));
    float* proj0        = (float*)take(N_NODES * sizeof(float));
    float* proj1        = (float*)take(N_NODES * sizeof(float));
    u16*   rel_bf       = (u16*)take((size_t)R_REL * D_DIM * sizeof(u16));
    u16*   fbf0         = (u16*)take((size_t)N_NODES * D_DIM * sizeof(u16));
    u16*   fbf1         = (u16*)take((size_t)N_NODES * D_DIM * sizeof(u16));
    u16*   fbf2         = (u16*)take((size_t)N_NODES * D_DIM * sizeof(u16));
    u16*   fbf3         = (u16*)take((size_t)N_NODES * D_DIM * sizeof(u16));

    k_tanh<<<(N_NODES * D_DIM / 4 + 255) / 256, 256, 0, stream>>>(features, out, fbf0);
    k_relprep<<<R_REL, 64, 0, stream>>>(rel_emb, attk, norm_r, dotk);
    k_pack_rel<<<(R_REL * 16 + 255) / 256, 256, 0, stream>>>(rel_emb, rel_bf);
    k_rowptr2<<<(2 * (N_NODES + 1) + 255) / 256, 256, 0, stream>>>(
        adj, high_nei, row_ptr_adj, row_ptr_high);

    int row_blocks = (N_NODES + 3) / 4;

    k_nr_layer<<<row_blocks, 256, 0, stream>>>(
        out, 1 * D_DIM, fbf0, fbf1,
        row_ptr_adj, adj + T_TRI, r_index + T_TRI, r_val,
        rel_bf, norm_r, dotk + 0 * R_REL, nullptr, nullptr);
    k_nr_layer<<<row_blocks, 256, 0, stream>>>(
        out, 2 * D_DIM, fbf1, fbf2,
        row_ptr_adj, adj + T_TRI, r_index + T_TRI, r_val,
        rel_bf, norm_r, dotk + 1 * R_REL, high_atts + 0 * D_DIM, proj0);
    k_high_layer<<<row_blocks, 256, 0, stream>>>(
        out, 3 * D_DIM, fbf2, fbf3,
        row_ptr_high, high_nei + T_TRI, proj0, high_atts + 1 * D_DIM, proj1);
    k_high_layer<<<row_blocks, 256, 0, stream>>>(
        out, 4 * D_DIM, fbf3, nullptr,
        row_ptr_high, high_nei + T_TRI, proj1, nullptr, nullptr);
}

// Round 7
// 295.479 us; speedup vs baseline: 1.2708x; 1.0104x over previous
//
#include <hip/hip_runtime.h>
#include <math.h>

#define N_NODES 100000
#define R_REL   1000
#define T_TRI   600000
#define D_DIM   128
#define OUT_STRIDE 640

typedef unsigned int  u32;
typedef unsigned short u16;

__device__ __forceinline__ float wave_sum(float v) {
    #pragma unroll
    for (int off = 32; off > 0; off >>= 1) v += __shfl_xor(v, off);
    return v;
}
__device__ __forceinline__ float sub16_sum(float v) {
    v += __shfl_xor(v, 1); v += __shfl_xor(v, 2);
    v += __shfl_xor(v, 4); v += __shfl_xor(v, 8);
    return v;
}
__device__ __forceinline__ float fast_tanh(float x) {
    float e = __expf(2.f * x);
    return 1.f - __fdividef(2.f, e + 1.f);
}
__device__ __forceinline__ float4 tanh4(float4 v) {
    float4 o; o.x = fast_tanh(v.x); o.y = fast_tanh(v.y);
    o.z = fast_tanh(v.z); o.w = fast_tanh(v.w);
    return o;
}
__device__ __forceinline__ float dot4(float4 a, float4 b) {
    return a.x*b.x + a.y*b.y + a.z*b.z + a.w*b.w;
}
// bf16 helpers: packed pairs, little-endian (elem 2i low, 2i+1 high), RNE pack
__device__ __forceinline__ u32 bfr(float x) {
    u32 u = __float_as_uint(x);
    return (u + 0x7fffu + ((u >> 16) & 1u)) >> 16;
}
__device__ __forceinline__ uint2 pack_bf4(float4 v) {
    uint2 p;
    p.x = bfr(v.x) | (bfr(v.y) << 16);
    p.y = bfr(v.z) | (bfr(v.w) << 16);
    return p;
}
__device__ __forceinline__ void unpack_bf8(uint4 v, float f[8]) {
    f[0] = __uint_as_float(v.x << 16); f[1] = __uint_as_float(v.x & 0xffff0000u);
    f[2] = __uint_as_float(v.y << 16); f[3] = __uint_as_float(v.y & 0xffff0000u);
    f[4] = __uint_as_float(v.z << 16); f[5] = __uint_as_float(v.z & 0xffff0000u);
    f[6] = __uint_as_float(v.w << 16); f[7] = __uint_as_float(v.w & 0xffff0000u);
}

// chunk0: f32 to out + bf16 copy to ws
__global__ void k_tanh(const float* __restrict__ feat, float* __restrict__ out,
                       u16* __restrict__ bf0) {
    int i = blockIdx.x * blockDim.x + threadIdx.x;
    if (i >= N_NODES * D_DIM / 4) return;
    int n  = i / (D_DIM / 4);
    int d4 = i % (D_DIM / 4);
    float4 v = reinterpret_cast<const float4*>(feat)[i];
    float4 t = tanh4(v);
    reinterpret_cast<float4*>(out + (size_t)n * OUT_STRIDE)[d4] = t;
    reinterpret_cast<uint2*>(bf0 + (size_t)n * D_DIM)[d4] = pack_bf4(t);
}

// per-relation tables: wtab[l][r] = exp(rel.attk_l / ||rel||),  fsc[r] = 2/||rel||^2
__global__ void k_relprep(const float* __restrict__ rel, const float* __restrict__ attk,
                          float* __restrict__ wtab, float* __restrict__ fsc) {
    int r = blockIdx.x;
    int lane = threadIdx.x;
    float a0 = rel[r * D_DIM + lane], a1 = rel[r * D_DIM + 64 + lane];
    float nrm2 = wave_sum(a0 * a0 + a1 * a1);
    float d0  = wave_sum(a0 * attk[lane] + a1 * attk[64 + lane]);
    float d1  = wave_sum(a0 * attk[D_DIM + lane] + a1 * attk[D_DIM + 64 + lane]);
    if (lane == 0) {
        float inv = __frsqrt_rn(nrm2);          // 1/||rel||  (||rel||>0 a.s.)
        wtab[r]         = __expf(d0 * inv);
        wtab[R_REL + r] = __expf(d1 * inv);
        fsc[r] = 2.f * inv * inv;
    }
}

__global__ void k_pack_rel(const float* __restrict__ rel, u16* __restrict__ relbf) {
    int t = blockIdx.x * blockDim.x + threadIdx.x;
    if (t >= R_REL * 16) return;
    int r = t >> 4, k = t & 15;
    const float4* src = (const float4*)(rel + (size_t)r * D_DIM + k * 8);
    uint2 pa = pack_bf4(src[0]), pb = pack_bf4(src[1]);
    uint4 o; o.x = pa.x; o.y = pa.y; o.z = pb.x; o.w = pb.y;
    ((uint4*)(relbf + (size_t)r * D_DIM))[k] = o;
}

__global__ void k_rowptr2(const int* __restrict__ rows_a, const int* __restrict__ rows_b,
                          int* __restrict__ pa, int* __restrict__ pb) {
    int i = blockIdx.x * blockDim.x + threadIdx.x;
    const int* rows; int* p; int n;
    if (i <= N_NODES) { rows = rows_a; p = pa; n = i; }
    else {
        n = i - (N_NODES + 1);
        if (n > N_NODES) return;
        rows = rows_b; p = pb;
    }
    int lo = 0, hi = T_TRI;
    while (lo < hi) { int mid = (lo + hi) >> 1; if (rows[mid] < n) lo = mid + 1; else hi = mid; }
    p[n] = lo;
}

// One wave per row, 4 subgroups x 16 lanes, one triple/subgroup/iter, 8 dims/lane.
// Softmax weights are pure per-relation table lookups (no max pass, no exp, no
// division in-kernel).  Gathers read bf16 rows; math in f32.
__global__ __launch_bounds__(256) void k_nr_layer(
    float* __restrict__ outbuf, int out_off,
    const u16* __restrict__ in_bf,
    u16* __restrict__ out_bf,           // nullable
    const int* __restrict__ row_ptr,
    const int* __restrict__ col,
    const int* __restrict__ ridx1,
    const float* __restrict__ r_val,
    const u16* __restrict__ rel_bf,
    const float* __restrict__ wtab,
    const float* __restrict__ fsc,
    const float* __restrict__ ha,       // nullable
    float* __restrict__ eproj_out) {
    __shared__ float s_w[4][64];
    __shared__ float s_fs[4][64];
    int wslot = threadIdx.x >> 6;
    int lane  = threadIdx.x & 63;
    int wid   = (blockIdx.x * blockDim.x + threadIdx.x) >> 6;
    if (wid >= N_NODES) return;
    int beg = row_ptr[wid], end = row_ptr[wid + 1];
    int deg = end - beg;
    float* orow = outbuf + (size_t)wid * OUT_STRIDE + out_off;
    int sg = lane >> 4, sl = lane & 15;

    if (deg == 0) {
        if (lane < 32) { float4 z = {0.f,0.f,0.f,0.f}; ((float4*)orow)[lane] = z; }
        if (out_bf != nullptr && lane < 16) {
            uint4 z = {0u,0u,0u,0u};
            ((uint4*)(out_bf + (size_t)wid * D_DIM))[lane] = z;
        }
        if (ha != nullptr && lane == 0) eproj_out[wid] = 1.f;   // exp(0)
        return;
    }

    // ---- pass A: per-lane table lookups (lane i owns triple beg+i) ----
    int  t0 = beg + lane;
    bool va = t0 < end;
    int  ta = va ? t0 : beg;
    int  rt_a = ridx1[ta];
    float rv_a = r_val[ta];
    bool  z_a  = (rv_a == 0.f);
    float w_a  = z_a ? 1.f : wtab[rt_a];
    float fs_a = z_a ? 0.f : fsc[rt_a];
    w_a = va ? w_a : 0.f;

    // ---- pre-issue iter0 + iter1 gathers (independent of the sum) ----
    int  tb0 = beg + sg, tb1 = tb0 + 4;
    bool v0 = tb0 < end, v1 = tb1 < end;
    int  tc0 = v0 ? tb0 : beg, tc1 = v1 ? tb1 : beg;
    int  cc0 = col[tc0],   cc1 = col[tc1];
    int  rr0 = ridx1[tc0], rr1 = ridx1[tc1];
    uint4 F0 = ((const uint4*)(in_bf  + (size_t)cc0 * D_DIM))[sl];
    uint4 R0 = ((const uint4*)(rel_bf + (size_t)rr0 * D_DIM))[sl];
    uint4 F1 = ((const uint4*)(in_bf  + (size_t)cc1 * D_DIM))[sl];
    uint4 R1 = ((const uint4*)(rel_bf + (size_t)rr1 * D_DIM))[sl];

    // ---- row sum (single butterfly; overlaps in-flight gathers) ----
    float lsum = w_a;
    for (int t = t0 + 64; t < end; t += 64) {          // deg>64 guard
        int rt = ridx1[t]; float rv = r_val[t];
        lsum += (rv == 0.f) ? 1.f : wtab[rt];
    }
    float inv_s = 1.f / wave_sum(lsum);
    s_w[wslot][lane]  = w_a * inv_s;
    s_fs[wslot][lane] = fs_a;
    // same wave writes & reads: no barrier needed

    // ---- iter 0 compute ----
    float w0  = v0 ? s_w[wslot][sg] : 0.f;
    float fs0 = s_fs[wslot][sg];
    float nf[8], rf[8];
    unpack_bf8(F0, nf); unpack_bf8(R0, rf);
    float pd = 0.f;
    #pragma unroll
    for (int j = 0; j < 8; ++j) pd += nf[j] * rf[j];
    pd = sub16_sum(pd);
    float f0 = fs0 * pd;
    float acc[8];
    #pragma unroll
    for (int j = 0; j < 8; ++j) acc[j] = w0 * (nf[j] - f0 * rf[j]);

    // ---- steady state: wave-uniform, 2-deep pipelined ----
    int niter = (deg + 3) >> 2;
    int cur_tc = tc1, cur_rr = rr1; bool cur_v = v1;
    for (int it = 1; it < niter; ++it) {
        int tb = beg + 4 * (it + 1) + sg;
        bool nv = tb < end;
        int  ntc = nv ? tb : beg;
        int  ncc = col[ntc];
        int  nrr = ridx1[ntc];
        uint4 NF = ((const uint4*)(in_bf  + (size_t)ncc * D_DIM))[sl];
        uint4 NR = ((const uint4*)(rel_bf + (size_t)nrr * D_DIM))[sl];

        int idx = 4 * it + sg;
        float w, fs;
        if (idx < 64) {
            w  = cur_v ? s_w[wslot][idx] : 0.f;
            fs = s_fs[wslot][idx];
        } else {                                        // deg>64 fallback
            float rv = r_val[cur_tc];
            bool z = (rv == 0.f);
            w  = cur_v ? (z ? 1.f : wtab[cur_rr]) * inv_s : 0.f;
            fs = z ? 0.f : fsc[cur_rr];
        }
        float gf[8], qf[8];
        unpack_bf8(F1, gf); unpack_bf8(R1, qf);
        float pdt = 0.f;
        #pragma unroll
        for (int j = 0; j < 8; ++j) pdt += gf[j] * qf[j];
        pdt = sub16_sum(pdt);
        float ft = fs * pdt;
        #pragma unroll
        for (int j = 0; j < 8; ++j) acc[j] += w * (gf[j] - ft * qf[j]);

        F1 = NF; R1 = NR;
        cur_tc = ntc; cur_rr = nrr; cur_v = nv;
    }

    // combine 4 subgroup partials (lanes sl, sl+16, sl+32, sl+48 share dims)
    #pragma unroll
    for (int j = 0; j < 8; ++j) {
        acc[j] += __shfl_xor(acc[j], 16);
        acc[j] += __shfl_xor(acc[j], 32);
    }
    float4 tv0 = tanh4(make_float4(acc[0], acc[1], acc[2], acc[3]));
    float4 tv1 = tanh4(make_float4(acc[4], acc[5], acc[6], acc[7]));
    // lane sl owns dims 8sl..8sl+7 -> float4 indices 2sl, 2sl+1
    if (sg == 0) ((float4*)orow)[2 * sl] = tv0;
    else if (sg == 1) ((float4*)orow)[2 * sl + 1] = tv1;
    if (out_bf != nullptr) {
        u16* rowbf = out_bf + (size_t)wid * D_DIM;
        if (sg == 0) ((uint2*)rowbf)[2 * sl] = pack_bf4(tv0);
        else if (sg == 1) ((uint2*)rowbf)[2 * sl + 1] = pack_bf4(tv1);
    }
    if (ha != nullptr) {
        const float4* ha4 = (const float4*)ha;
        float pdp = dot4(tv0, ha4[2 * sl]) + dot4(tv1, ha4[2 * sl + 1]);
        pdp = sub16_sum(pdp);
        if (lane == 0) eproj_out[wid] = __expf(pdp);
    }
}

__global__ __launch_bounds__(256) void k_high_layer(
    float* __restrict__ outbuf, int out_off,
    const u16* __restrict__ in_bf,
    u16* __restrict__ out_bf,           // nullable
    const int* __restrict__ row_ptr,
    const int* __restrict__ hcol,
    const float* __restrict__ eproj,    // exp(proj) per node
    const float* __restrict__ ha,       // nullable
    float* __restrict__ eproj_out) {
    __shared__ float s_w[4][64];
    int wslot = threadIdx.x >> 6;
    int lane  = threadIdx.x & 63;
    int wid   = (blockIdx.x * blockDim.x + threadIdx.x) >> 6;
    if (wid >= N_NODES) return;
    int beg = row_ptr[wid], end = row_ptr[wid + 1];
    int deg = end - beg;
    float* orow = outbuf + (size_t)wid * OUT_STRIDE + out_off;
    int sg = lane >> 4, sl = lane & 15;

    if (deg == 0) {
        if (lane < 32) { float4 z = {0.f,0.f,0.f,0.f}; ((float4*)orow)[lane] = z; }
        if (out_bf != nullptr && lane < 16) {
            uint4 z = {0u,0u,0u,0u};
            ((uint4*)(out_bf + (size_t)wid * D_DIM))[lane] = z;
        }
        if (ha != nullptr && lane == 0) eproj_out[wid] = 1.f;   // exp(0)
        return;
    }

    int  t0 = beg + lane;
    bool va = t0 < end;
    int  ta = va ? t0 : beg;
    int  c_a = hcol[ta];
    float e_a = eproj[c_a];
    e_a = va ? e_a : 0.f;

    // pre-issue iter0 + iter1 gathers
    int  tb0 = beg + sg, tb1 = tb0 + 4;
    bool v0 = tb0 < end, v1 = tb1 < end;
    int  tc0 = v0 ? tb0 : beg, tc1 = v1 ? tb1 : beg;
    int  cc0 = hcol[tc0], cc1 = hcol[tc1];
    uint4 F0 = ((const uint4*)(in_bf + (size_t)cc0 * D_DIM))[sl];
    uint4 F1 = ((const uint4*)(in_bf + (size_t)cc1 * D_DIM))[sl];

    float lsum = e_a;
    for (int t = t0 + 64; t < end; t += 64)            // deg>64 guard
        lsum += eproj[hcol[t]];
    float inv_s = 1.f / wave_sum(lsum);
    s_w[wslot][lane] = e_a * inv_s;

    float w0 = v0 ? s_w[wslot][sg] : 0.f;
    float nf[8];
    unpack_bf8(F0, nf);
    float acc[8];
    #pragma unroll
    for (int j = 0; j < 8; ++j) acc[j] = w0 * nf[j];

    int niter = (deg + 3) >> 2;
    int cur_cc = cc1; bool cur_v = v1;
    for (int it = 1; it < niter; ++it) {
        int tb = beg + 4 * (it + 1) + sg;
        bool nv = tb < end;
        int  ntc = nv ? tb : beg;
        int  ncc = hcol[ntc];
        uint4 NF = ((const uint4*)(in_bf + (size_t)ncc * D_DIM))[sl];

        int idx = 4 * it + sg;
        float w;
        if (idx < 64) w = cur_v ? s_w[wslot][idx] : 0.f;
        else          w = cur_v ? eproj[cur_cc] * inv_s : 0.f;
        float gf[8];
        unpack_bf8(F1, gf);
        #pragma unroll
        for (int j = 0; j < 8; ++j) acc[j] += w * gf[j];

        F1 = NF; cur_cc = ncc; cur_v = nv;
    }

    #pragma unroll
    for (int j = 0; j < 8; ++j) {
        acc[j] += __shfl_xor(acc[j], 16);
        acc[j] += __shfl_xor(acc[j], 32);
    }
    float4 tv0 = tanh4(make_float4(acc[0], acc[1], acc[2], acc[3]));
    float4 tv1 = tanh4(make_float4(acc[4], acc[5], acc[6], acc[7]));
    if (sg == 0) ((float4*)orow)[2 * sl] = tv0;
    else if (sg == 1) ((float4*)orow)[2 * sl + 1] = tv1;
    if (out_bf != nullptr) {
        u16* rowbf = out_bf + (size_t)wid * D_DIM;
        if (sg == 0) ((uint2*)rowbf)[2 * sl] = pack_bf4(tv0);
        else if (sg == 1) ((uint2*)rowbf)[2 * sl + 1] = pack_bf4(tv1);
    }
    if (ha != nullptr) {
        const float4* ha4 = (const float4*)ha;
        float pdp = dot4(tv0, ha4[2 * sl]) + dot4(tv1, ha4[2 * sl + 1]);
        pdp = sub16_sum(pdp);
        if (lane == 0) eproj_out[wid] = __expf(pdp);
    }
}

extern "C" void kernel_launch(void* const* d_in, const int* in_sizes, int n_in,
                              void* d_out, int out_size, void* d_ws, size_t ws_size,
                              hipStream_t stream) {
    const float* features  = (const float*)d_in[0];
    const float* rel_emb   = (const float*)d_in[1];
    const float* r_val     = (const float*)d_in[2];
    const float* attk      = (const float*)d_in[3];
    const float* high_atts = (const float*)d_in[4];
    const int*   adj       = (const int*)d_in[5];
    const int*   r_index   = (const int*)d_in[6];
    const int*   high_nei  = (const int*)d_in[7];
    float* out = (float*)d_out;

    char* ws = (char*)d_ws;
    auto take = [&](size_t bytes) -> char* {
        char* p = ws;
        ws += (bytes + 255) & ~(size_t)255;
        return p;
    };
    int*   row_ptr_adj  = (int*)take((N_NODES + 1) * sizeof(int));
    int*   row_ptr_high = (int*)take((N_NODES + 1) * sizeof(int));
    float* wtab         = (float*)take(2 * R_REL * sizeof(float));
    float* fsc          = (float*)take(R_REL * sizeof(float));
    float* eproj0       = (float*)take(N_NODES * sizeof(float));
    float* eproj1       = (float*)take(N_NODES * sizeof(float));
    u16*   rel_bf       = (u16*)take((size_t)R_REL * D_DIM * sizeof(u16));
    u16*   fbf0         = (u16*)take((size_t)N_NODES * D_DIM * sizeof(u16));
    u16*   fbf1         = (u16*)take((size_t)N_NODES * D_DIM * sizeof(u16));
    u16*   fbf2         = (u16*)take((size_t)N_NODES * D_DIM * sizeof(u16));
    u16*   fbf3         = (u16*)take((size_t)N_NODES * D_DIM * sizeof(u16));

    k_tanh<<<(N_NODES * D_DIM / 4 + 255) / 256, 256, 0, stream>>>(features, out, fbf0);
    k_relprep<<<R_REL, 64, 0, stream>>>(rel_emb, attk, wtab, fsc);
    k_pack_rel<<<(R_REL * 16 + 255) / 256, 256, 0, stream>>>(rel_emb, rel_bf);
    k_rowptr2<<<(2 * (N_NODES + 1) + 255) / 256, 256, 0, stream>>>(
        adj, high_nei, row_ptr_adj, row_ptr_high);

    int row_blocks = (N_NODES + 3) / 4;

    k_nr_layer<<<row_blocks, 256, 0, stream>>>(
        out, 1 * D_DIM, fbf0, fbf1,
        row_ptr_adj, adj + T_TRI, r_index + T_TRI, r_val,
        rel_bf, wtab + 0 * R_REL, fsc, nullptr, nullptr);
    k_nr_layer<<<row_blocks, 256, 0, stream>>>(
        out, 2 * D_DIM, fbf1, fbf2,
        row_ptr_adj, adj + T_TRI, r_index + T_TRI, r_val,
        rel_bf, wtab + 1 * R_REL, fsc, high_atts + 0 * D_DIM, eproj0);
    k_high_layer<<<row_blocks, 256, 0, stream>>>(
        out, 3 * D_DIM, fbf2, fbf3,
        row_ptr_high, high_nei + T_TRI, eproj0, high_atts + 1 * D_DIM, eproj1);
    k_high_layer<<<row_blocks, 256, 0, stream>>>(
        out, 4 * D_DIM, fbf3, nullptr,
        row_ptr_high, high_nei + T_TRI, eproj1, nullptr, nullptr);
}